// Round 14
// baseline (160.189 us; speedup 1.0000x reference)
//
#include <hip/hip_runtime.h>
#include <hip/hip_bf16.h>
#include <math.h>

#define HEADS 12
#define NSEQ 1024
#define BATCH 8
#define FDIM 769
#define KP 800                      // padded K dim
#define NROWS (BATCH*NSEQ)          // 8192
#define BH (BATCH*HEADS)            // 96
#define BHROWS (BH*NSEQ)            // 98304
#define LSTR 40                     // LDS row stride in ushorts (padded: 20 dwords, kills 4-way bank conflicts)

typedef __attribute__((ext_vector_type(8))) short bf16x8_t;
typedef __attribute__((ext_vector_type(4))) short bf16x4_t;
typedef __attribute__((ext_vector_type(4))) float f32x4_t;

__device__ __forceinline__ unsigned short f2bf(float f){
    unsigned u = __float_as_uint(f);
    return (unsigned short)((u + 0x7FFFu + ((u >> 16) & 1u)) >> 16);
}

__device__ __forceinline__ float fast_rcp(float x){
    return __builtin_amdgcn_rcpf(x);
}
__device__ __forceinline__ float fast_exp2(float x){
    return __builtin_amdgcn_exp2f(x);
}

// ---------------- x (8192x769 f32) -> xb (8192x800 bf16, zero pad) ----------------
__global__ __launch_bounds__(256) void conv_x(const float* __restrict__ x, ushort* __restrict__ xb){
    int idx = blockIdx.x*256 + threadIdx.x;          // 8192*200
    int r = idx / 200, c4 = (idx % 200) * 4;
    const float* row = x + (size_t)r * FDIM;
    ushort4 o;
    o.x = (c4+0 < FDIM) ? f2bf(row[c4+0]) : (ushort)0;
    o.y = (c4+1 < FDIM) ? f2bf(row[c4+1]) : (ushort)0;
    o.z = (c4+2 < FDIM) ? f2bf(row[c4+2]) : (ushort)0;
    o.w = (c4+3 < FDIM) ? f2bf(row[c4+3]) : (ushort)0;
    *(ushort4*)(xb + (size_t)r*KP + c4) = o;
}

// ------- W transpose+convert: WcatT[mat*768+n][k]=W[k][n+1]; WoT[n][k']=Wo[perm(k')][n+1] -------
__global__ __launch_bounds__(256) void conv_w(const float* __restrict__ Wq, const float* __restrict__ Wk,
                                              const float* __restrict__ Wv, const float* __restrict__ Wo,
                                              ushort* __restrict__ WcatT, ushort* __restrict__ WoT){
    int kt = blockIdx.x, nt = blockIdx.y, mat = blockIdx.z;
    const float* W = (mat==0)?Wq:(mat==1)?Wk:(mat==2)?Wv:Wo;
    __shared__ float T[32][33];
    int t = threadIdx.x;
    #pragma unroll
    for (int p=0; p<4; p++){
        int idx = t + p*256;
        int kk = idx>>5, nn = idx&31;
        int kp = kt*32 + kk;
        int srck;
        if (mat < 3) srck = (kp < FDIM) ? kp : -1;
        else         srck = (kp < 768) ? kp+1 : ((kp==768) ? 0 : -1);
        T[kk][nn] = (srck >= 0) ? W[(size_t)srck*FDIM + (nt*32+nn) + 1] : 0.0f;
    }
    __syncthreads();
    ushort* outp = (mat < 3) ? (WcatT + (size_t)mat*768*KP) : WoT;
    #pragma unroll
    for (int p=0; p<4; p++){
        int idx = t + p*256;
        int nl = idx>>5, kk = idx&31;
        outp[(size_t)(nt*32+nl)*KP + kt*32 + kk] = f2bf(T[kk][nl]);
    }
}

// ---------------- fused QKV GEMM: xb(8192x800) @ WcatT^T -> head-split bf16 + fp32 times ----------------
__global__ __launch_bounds__(256) void gemm_qkv(const ushort* __restrict__ A, const ushort* __restrict__ Bt,
                                                ushort* __restrict__ qkv, float* __restrict__ tbuf){
    __shared__ __align__(16) ushort As[2][128*LSTR];
    __shared__ __align__(16) ushort Bs[2][128*LSTR];
    const int m0 = blockIdx.x*128, n0 = blockIdx.y*128;
    const int tid = threadIdx.x, lane = tid&63, wave = tid>>6;
    const int wm = wave>>1, wn = wave&1;
    const int g = lane>>4, c = lane&15;

    f32x4_t acc[4][4];
    #pragma unroll
    for (int i=0;i<4;i++)
        #pragma unroll
        for (int j=0;j<4;j++) acc[i][j] = (f32x4_t){0.f,0.f,0.f,0.f};

    bf16x8_t ra[2], rb[2];
    auto LOADS = [&](int kt){
        int k0 = kt*32;
        #pragma unroll
        for (int p=0;p<2;p++){
            int idx = tid + p*256;
            int row = idx>>2, ch = idx&3;
            ra[p] = *(const bf16x8_t*)(A  + (size_t)(m0+row)*KP + k0 + ch*8);
            rb[p] = *(const bf16x8_t*)(Bt + (size_t)(n0+row)*KP + k0 + ch*8);
        }
    };
    auto WRITES = [&](int buf){
        #pragma unroll
        for (int p=0;p<2;p++){
            int idx = tid + p*256;
            int row = idx>>2, ch = idx&3;
            int sw = (ch ^ (row&3))*8;
            *(bf16x8_t*)&As[buf][row*LSTR + sw] = ra[p];
            *(bf16x8_t*)&Bs[buf][row*LSTR + sw] = rb[p];
        }
    };

    LOADS(0); WRITES(0); __syncthreads();
    for (int kt=0; kt<25; kt++){
        int cur = kt&1;
        if (kt+1 < 25) LOADS(kt+1);
        bf16x8_t af[4], bf[4];
        #pragma unroll
        for (int mf=0; mf<4; mf++){
            int row = wm*64 + mf*16 + c;
            af[mf] = *(const bf16x8_t*)&As[cur][row*LSTR + ((g ^ (row&3))*8)];
        }
        #pragma unroll
        for (int nf=0; nf<4; nf++){
            int row = wn*64 + nf*16 + c;
            bf[nf] = *(const bf16x8_t*)&Bs[cur][row*LSTR + ((g ^ (row&3))*8)];
        }
        #pragma unroll
        for (int mf=0; mf<4; mf++)
            #pragma unroll
            for (int nf=0; nf<4; nf++)
                acc[mf][nf] = __builtin_amdgcn_mfma_f32_16x16x32_bf16(af[mf], bf[nf], acc[mf][nf], 0,0,0);
        if (kt+1 < 25) WRITES(cur^1);
        __syncthreads();
    }

    const int nb = n0 + wn*64;
    const int matv = nb / 768;
    const int hh = (nb % 768) / 64;
    #pragma unroll
    for (int mf=0; mf<4; mf++){
        #pragma unroll
        for (int j=0; j<4; j++){
            int m = m0 + wm*64 + mf*16 + g*4 + j;
            int bb = m >> 10, ns = m & (NSEQ-1);
            size_t rowidx = ((size_t)bb*HEADS + hh)*NSEQ + ns;
            size_t sbase = (size_t)matv*((size_t)BHROWS*64) + rowidx*64;
            float sum = 0.f;
            #pragma unroll
            for (int nf=0; nf<4; nf++){
                float v = acc[mf][nf][j];
                qkv[sbase + nf*16 + c] = f2bf(v);
                sum += v*v;
            }
            sum += __shfl_xor(sum,1,64); sum += __shfl_xor(sum,2,64);
            sum += __shfl_xor(sum,4,64); sum += __shfl_xor(sum,8,64);
            if (c == 0) tbuf[(size_t)matv*BHROWS + rowidx] = sqrtf(1.0f + sum);
        }
    }
}

// ---------------- V transpose: vsp[bh][i][d] -> vT[bh][d][i] ----------------
__global__ __launch_bounds__(256) void transpose_v(const ushort* __restrict__ vsp, ushort* __restrict__ vT){
    const int bh = blockIdx.x >> 3, it128 = blockIdx.x & 7;
    __shared__ ushort T2[64*136];                    // [d][128 i + 8 pad]
    const int tid = threadIdx.x;
    {
        int ii = tid>>1, half = tid&1;
        const ushort* src = vsp + ((size_t)bh*NSEQ + it128*128 + ii)*64 + half*32;
        bf16x8_t rr[4];
        #pragma unroll
        for (int p=0;p<4;p++) rr[p] = *(const bf16x8_t*)(src + p*8);
        #pragma unroll
        for (int p=0;p<4;p++)
            #pragma unroll
            for (int e=0;e<8;e++)
                T2[(half*32 + p*8 + e)*136 + ii] = (ushort)rr[p][e];
    }
    __syncthreads();
    {
        int dd = tid>>2, qq = tid&3;
        ushort* dst = vT + ((size_t)bh*64 + dd)*NSEQ + it128*128 + qq*32;
        #pragma unroll
        for (int p=0;p<4;p++)
            *(bf16x8_t*)(dst + p*8) = *(const bf16x8_t*)&T2[dd*136 + qq*32 + p*8];
    }
}

// ---------------- fused Lorentz flash attention (4 waves x 32 j, K=32 PV, sigma-permuted V) ----------------
__global__ __launch_bounds__(256, 3) void lorentz_attn(
    const ushort* __restrict__ qsp, const ushort* __restrict__ ksp, const ushort* __restrict__ vT,
    const float* __restrict__ qtg, const float* __restrict__ ktg, const float* __restrict__ vtg,
    ushort* __restrict__ merged, float* __restrict__ ct)
{
    const int lin = blockIdx.x;
    const int bh = lin % BH;             // same-bh blocks are 96 apart
    const int jt = lin / BH;             // 0..7
    const int b = bh / HEADS, h = bh % HEADS;
    const size_t rb = (size_t)bh * NSEQ;

    // per buffer: Qs 64x64 (4096) | Vt 80x64 (5120) = 9216 ushorts; K-stage unions buf0[0..8191]
    __shared__ __align__(16) ushort QVbuf[2][9216];
    __shared__ __align__(16) float qts[2][64];
    __shared__ __align__(16) float kts[128];

    const int tid = threadIdx.x, lane = tid&63, wave = tid>>6;   // wave 0..3
    const int g = lane>>4, c = lane&15;

    ushort* Kst = &QVbuf[0][0];

    bf16x8_t rq[2], rv[2]; float rqt = 0.f, rvt = 0.f;
    const int sr = tid>>2, sch = tid&3;            // staging: row 0..63, 16-elem chunk 0..3
    auto LOADQV = [&](int it){
        int i0 = it*64;
        const ushort* qp = qsp + (rb + i0 + sr)*64 + sch*16;
        rq[0] = *(const bf16x8_t*)(qp);
        rq[1] = *(const bf16x8_t*)(qp + 8);
        const ushort* vp = vT + ((size_t)bh*64 + sr)*NSEQ + i0 + sch*16;
        rv[0] = *(const bf16x8_t*)(vp);
        rv[1] = *(const bf16x8_t*)(vp + 8);
        if (tid < 64) rqt = qtg[rb + i0 + tid];
        else if (tid < 128) rvt = vtg[rb + i0 + (tid-64)];
    };
    // sigma-permuted V store: position p = ib2*32 + 8*gp + 4*h2 + l holds i = ib2*32 + 16*h2 + 4*gp + l
    auto WRITEQV = [&](int buf){
        ushort* Qb = &QVbuf[buf][0];
        ushort* Vb = &QVbuf[buf][4096];
        *(bf16x8_t*)&Qb[sr*64 + (((2*sch  ) ^ (sr&7))*8)] = rq[0];
        *(bf16x8_t*)&Qb[sr*64 + (((2*sch+1) ^ (sr&7))*8)] = rq[1];
        int pbase = (sch>>1)*32 + (sch&1)*4;       // ib2*32 + 4*h2
        int sx = (sr&7)*8;
        #pragma unroll
        for (int s=0; s<4; s++){
            bf16x4_t sl = (s&1) ? (bf16x4_t)__builtin_shufflevector(rv[s>>1], rv[s>>1], 4,5,6,7)
                                : (bf16x4_t)__builtin_shufflevector(rv[s>>1], rv[s>>1], 0,1,2,3);
            *(bf16x4_t*)&Vb[sr*64 + ((pbase + 8*s) ^ sx)] = sl;
        }
        if (tid < 64) qts[buf][tid] = rqt;
        else if (tid < 128){
            int i = tid - 64;
            int p = 32*(i>>5) + 8*((i>>2)&3) + 4*((i>>4)&1) + (i&3);
            Vb[64*64 + p] = f2bf(rvt);
        }
    };

    // prologue: prefetch tile 0, stage K, zero V pads
    LOADQV(0);
    {
        int row = tid>>1, half = tid&1;
        const ushort* kp = ksp + (rb + jt*128 + row)*64 + half*32;
        #pragma unroll
        for (int p=0; p<4; p++){
            bf16x8_t kr = *(const bf16x8_t*)(kp + p*8);
            int c8 = half*4 + p;
            *(bf16x8_t*)&Kst[row*64 + ((c8 ^ (row&7))*8)] = kr;
        }
    }
    if (tid < 128) kts[tid] = ktg[rb + jt*128 + tid];
    for (int idx = tid; idx < 2*15*64; idx += 256){
        int bz = idx/(15*64), r2 = idx%(15*64);
        QVbuf[bz][4096 + (65 + (r2>>6))*64 + (r2&63)] = 0;
    }
    __syncthreads();

    // hoist K fragments + times (K LDS region dies after this barrier pair)
    bf16x8_t kfrag[2][2]; float kt2e[2];
    #pragma unroll
    for (int jf=0; jf<2; jf++){
        int krow = wave*32 + jf*16 + c;
        kfrag[jf][0] = *(const bf16x8_t*)&Kst[krow*64 + (((  g) ^ (krow&7))*8)];
        kfrag[jf][1] = *(const bf16x8_t*)&Kst[krow*64 + (((4+g) ^ (krow&7))*8)];
        kt2e[jf] = 5.43656365691809f * kts[krow];      // 2e * kt
    }
    __syncthreads();
    WRITEQV(0);
    __syncthreads();

    f32x4_t acc[2][5];
    #pragma unroll
    for (int jf=0; jf<2; jf++)
        #pragma unroll
        for (int dt=0; dt<5; dt++) acc[jf][dt] = (f32x4_t){0.f,0.f,0.f,0.f};

    for (int it=0; it<16; it++){
        int cur = it&1;
        if (it+1 < 16) LOADQV(it+1);
        ushort* Qc = &QVbuf[cur][0];
        ushort* Vc = &QVbuf[cur][4096];
        #pragma unroll
        for (int ib2=0; ib2<2; ib2++){
            // Q fragments for the two 16-row subtiles of this 32-i block
            bf16x8_t qf[2][2];
            #pragma unroll
            for (int t=0; t<2; t++){
                int qrow = ib2*32 + t*16 + c;
                qf[t][0] = *(const bf16x8_t*)&Qc[qrow*64 + (((  g) ^ (qrow&7))*8)];
                qf[t][1] = *(const bf16x8_t*)&Qc[qrow*64 + (((4+g) ^ (qrow&7))*8)];
            }
            f32x4_t qt0 = *(const f32x4_t*)&qts[cur][ib2*32 + g*4];
            f32x4_t qt1 = *(const f32x4_t*)&qts[cur][ib2*32 + 16 + g*4];
            // V fragments: K=32 B-frag, b128 at sigma positions
            bf16x8_t vf[5];
            #pragma unroll
            for (int dt=0; dt<5; dt++){
                int d = dt*16 + c;
                vf[dt] = *(const bf16x8_t*)&Vc[d*64 + ((ib2*32 + g*8) ^ ((d&7)*8))];
            }
            #pragma unroll
            for (int jf=0; jf<2; jf++){
                f32x4_t d0 = (f32x4_t){0.f,0.f,0.f,0.f};
                f32x4_t d1 = (f32x4_t){0.f,0.f,0.f,0.f};
                __builtin_amdgcn_s_setprio(1);
                d0 = __builtin_amdgcn_mfma_f32_16x16x32_bf16(qf[0][0], kfrag[jf][0], d0, 0,0,0);
                d0 = __builtin_amdgcn_mfma_f32_16x16x32_bf16(qf[0][1], kfrag[jf][1], d0, 0,0,0);
                d1 = __builtin_amdgcn_mfma_f32_16x16x32_bf16(qf[1][0], kfrag[jf][0], d1, 0,0,0);
                d1 = __builtin_amdgcn_mfma_f32_16x16x32_bf16(qf[1][1], kfrag[jf][1], d1, 0,0,0);
                __builtin_amdgcn_s_setprio(0);
                // w = exp(1/(1+ln(1+d2))) = exp2(1/(log2(e*(1+d2)) * ln2^2));
                // log2 via exponent bit-hack with 0.48045301 folded into the fma constants
                float w0[4], w1[4];
                #pragma unroll
                for (int r=0; r<4; r++){
                    float c0 = fmaf(qt0[r], kt2e[jf], -2.718281828f);
                    float s0 = fmaf(d0[r], -5.43656365691809f, c0);
                    float L0 = fmaf((float)__float_as_int(s0), 5.727461e-8f, -60.996868f);
                    w0[r] = fast_exp2(fast_rcp(L0));
                    float c1 = fmaf(qt1[r], kt2e[jf], -2.718281828f);
                    float s1 = fmaf(d1[r], -5.43656365691809f, c1);
                    float L1 = fmaf((float)__float_as_int(s1), 5.727461e-8f, -60.996868f);
                    w1[r] = fast_exp2(fast_rcp(L1));
                }
                union { __hip_bfloat162 h2[4]; bf16x8_t v8; } uu;
                uu.h2[0] = __float22bfloat162_rn(float2{w0[0], w0[1]});
                uu.h2[1] = __float22bfloat162_rn(float2{w0[2], w0[3]});
                uu.h2[2] = __float22bfloat162_rn(float2{w1[0], w1[1]});
                uu.h2[3] = __float22bfloat162_rn(float2{w1[2], w1[3]});
                bf16x8_t pa = uu.v8;
                __builtin_amdgcn_s_setprio(1);
                #pragma unroll
                for (int dt=0; dt<5; dt++)
                    acc[jf][dt] = __builtin_amdgcn_mfma_f32_16x16x32_bf16(pa, vf[dt], acc[jf][dt], 0,0,0);
                __builtin_amdgcn_s_setprio(0);
            }
        }
        if (it+1 < 16) WRITEQV(cur^1);
        __syncthreads();
    }

    // centroid normalize + stage output through LDS (reuse buf0 region)
    ushort* Ms = &QVbuf[0][0];
    #pragma unroll
    for (int jf=0; jf<2; jf++){
        #pragma unroll
        for (int r=0; r<4; r++){
            float part = 0.f;
            #pragma unroll
            for (int dt=0; dt<4; dt++) part += acc[jf][dt][r]*acc[jf][dt][r];
            part += __shfl_xor(part,1,64); part += __shfl_xor(part,2,64);
            part += __shfl_xor(part,4,64); part += __shfl_xor(part,8,64);
            float tv = acc[jf][4][r];
            float tb = __shfl(tv, lane & 48, 64);      // c==0 slot holds time accum
            float li = part - tb*tb;
            float f = rsqrtf(fmaxf(fabsf(li), 1e-6f));
            int jl = wave*32 + jf*16 + g*4 + r;
            #pragma unroll
            for (int dt=0; dt<4; dt++)
                Ms[jl*64 + dt*16 + c] = f2bf(acc[jf][dt][r]*f);
            if (c == 0)
                ct[((size_t)b*NSEQ + jt*128 + jl)*HEADS + h] = tb*f;
        }
    }
    __syncthreads();
    {
        int row = tid>>1, half = tid&1;
        size_t gb = ((size_t)b*NSEQ + jt*128 + row)*KP + h*64 + half*32;
        #pragma unroll
        for (int q4=0; q4<4; q4++)
            *(bf16x8_t*)(merged + gb + q4*8) = *(const bf16x8_t*)&Ms[row*64 + half*32 + q4*8];
    }
}

// ---- output GEMM: merged @ WoT^T -> out[:,1:769] fp32, + per-row partial sum-of-squares ----
__global__ __launch_bounds__(256) void gemm_out_k(const ushort* __restrict__ A, const ushort* __restrict__ Bt,
                                                  float* __restrict__ out, float* __restrict__ rowsum){
    __shared__ __align__(16) ushort As[2][128*LSTR];
    __shared__ __align__(16) ushort Bs[2][128*LSTR];
    const int m0 = blockIdx.x*128, n0 = blockIdx.y*128;
    const int tid = threadIdx.x, lane = tid&63, wave = tid>>6;
    const int wm = wave>>1, wn = wave&1;
    const int g = lane>>4, c = lane&15;

    f32x4_t acc[4][4];
    #pragma unroll
    for (int i=0;i<4;i++)
        #pragma unroll
        for (int j=0;j<4;j++) acc[i][j] = (f32x4_t){0.f,0.f,0.f,0.f};

    bf16x8_t ra[2], rb[2];
    auto LOADS = [&](int kt){
        int k0 = kt*32;
        #pragma unroll
        for (int p=0;p<2;p++){
            int idx = tid + p*256;
            int row = idx>>2, ch = idx&3;
            ra[p] = *(const bf16x8_t*)(A  + (size_t)(m0+row)*KP + k0 + ch*8);
            rb[p] = *(const bf16x8_t*)(Bt + (size_t)(n0+row)*KP + k0 + ch*8);
        }
    };
    auto WRITES = [&](int buf){
        #pragma unroll
        for (int p=0;p<2;p++){
            int idx = tid + p*256;
            int row = idx>>2, ch = idx&3;
            int sw = (ch ^ (row&3))*8;
            *(bf16x8_t*)&As[buf][row*LSTR + sw] = ra[p];
            *(bf16x8_t*)&Bs[buf][row*LSTR + sw] = rb[p];
        }
    };

    LOADS(0); WRITES(0); __syncthreads();
    for (int kt=0; kt<25; kt++){
        int cur = kt&1;
        if (kt+1 < 25) LOADS(kt+1);
        bf16x8_t af[4], bf[4];
        #pragma unroll
        for (int mf=0; mf<4; mf++){
            int row = wm*64 + mf*16 + c;
            af[mf] = *(const bf16x8_t*)&As[cur][row*LSTR + ((g ^ (row&3))*8)];
        }
        #pragma unroll
        for (int nf=0; nf<4; nf++){
            int row = wn*64 + nf*16 + c;
            bf[nf] = *(const bf16x8_t*)&Bs[cur][row*LSTR + ((g ^ (row&3))*8)];
        }
        #pragma unroll
        for (int mf=0; mf<4; mf++)
            #pragma unroll
            for (int nf=0; nf<4; nf++)
                acc[mf][nf] = __builtin_amdgcn_mfma_f32_16x16x32_bf16(af[mf], bf[nf], acc[mf][nf], 0,0,0);
        if (kt+1 < 25) WRITES(cur^1);
        __syncthreads();
    }

    const int slot = blockIdx.y*2 + wn;              // 0..11
    #pragma unroll
    for (int mf=0; mf<4; mf++){
        #pragma unroll
        for (int j=0; j<4; j++){
            int m = m0 + wm*64 + mf*16 + g*4 + j;
            float s = 0.f;
            #pragma unroll
            for (int nf=0; nf<4; nf++){
                float v = acc[mf][nf][j];
                out[(size_t)m*FDIM + 1 + n0 + wn*64 + nf*16 + c] = v;
                s = fmaf(v, v, s);
            }
            s += __shfl_xor(s,1,64); s += __shfl_xor(s,2,64);
            s += __shfl_xor(s,4,64); s += __shfl_xor(s,8,64);
            if (c == 0) rowsum[(size_t)slot*NROWS + m] = s;
        }
    }
}

// ------- merged[:,768(time)] = sqrt(max(sum_h ct^2 - 11, eps)); zero cols 769..799 -------
__global__ __launch_bounds__(256) void time_r_k(const float* __restrict__ ct, ushort* __restrict__ merged){
    int r = blockIdx.x*256 + threadIdx.x;
    float s = 0.f;
    #pragma unroll
    for (int hh=0; hh<HEADS; hh++){
        float t = ct[(size_t)r*HEADS + hh];
        s = fmaf(t, t, s);
    }
    bf16x8_t z = (bf16x8_t){0,0,0,0,0,0,0,0};
    bf16x8_t z0 = z;
    z0[0] = (short)f2bf(sqrtf(fmaxf(s - (float)(HEADS-1), 1e-6f)));
    ushort* dst = merged + (size_t)r*KP + 768;       // 16B aligned (1600r+1536)
    *(bf16x8_t*)(dst)      = z0;
    *(bf16x8_t*)(dst + 8)  = z;
    *(bf16x8_t*)(dst + 16) = z;
    *(bf16x8_t*)(dst + 24) = z;
}

// ---------------- out[:,0] = sqrt(1 + sum over 12 rowsum slots) ----------------
__global__ __launch_bounds__(256) void out_time(const float* __restrict__ rowsum, float* __restrict__ out)
{
    int r = blockIdx.x*256 + threadIdx.x;
    float s = 1.0f;
    #pragma unroll
    for (int k=0; k<12; k++) s += rowsum[(size_t)k*NROWS + r];
    out[(size_t)r*FDIM] = sqrtf(s);
}

extern "C" void kernel_launch(void* const* d_in, const int* in_sizes, int n_in,
                              void* d_out, int out_size, void* d_ws, size_t ws_size,
                              hipStream_t stream)
{
    const float* x  = (const float*)d_in[0];
    const float* Wq = (const float*)d_in[1];
    const float* Wk = (const float*)d_in[2];
    const float* Wv = (const float*)d_in[3];
    const float* Wo = (const float*)d_in[4];
    float* out = (float*)d_out;

    char* p = (char*)d_ws;
    ushort* xb     = (ushort*)p; p += (size_t)NROWS*KP*2;          // 13.1 MB
    ushort* WcatT  = (ushort*)p; p += (size_t)2304*KP*2;           //  3.7 MB
    ushort* WoT    = (ushort*)p; p += (size_t)768*KP*2;            //  1.2 MB
    ushort* qkv    = (ushort*)p; p += (size_t)3*BHROWS*64*2;       // 37.7 MB
    float*  tbuf   = (float*)p;  p += (size_t)3*BHROWS*4;          //  1.2 MB
    float*  ct     = (float*)p;  p += (size_t)NROWS*HEADS*4;       //  0.4 MB
    ushort* merged = (ushort*)p; p += (size_t)NROWS*KP*2;          // 13.1 MB
    ushort* vT     = (ushort*)p; p += (size_t)BH*64*NSEQ*2;        // 12.6 MB
    float*  rowsum = (float*)p;  p += (size_t)12*NROWS*4;          //  0.4 MB

    const size_t SP = (size_t)BHROWS*64;

    conv_x<<<6400, 256, 0, stream>>>(x, xb);
    conv_w<<<dim3(25,24,4), 256, 0, stream>>>(Wq, Wk, Wv, Wo, WcatT, WoT);
    gemm_qkv<<<dim3(64,18), 256, 0, stream>>>(xb, WcatT, qkv, tbuf);
    transpose_v<<<768, 256, 0, stream>>>(qkv + 2*SP, vT);
    lorentz_attn<<<768, 256, 0, stream>>>(qkv, qkv + SP, vT,
                                          tbuf, tbuf + BHROWS, tbuf + 2*BHROWS,
                                          merged, ct);
    time_r_k<<<NROWS/256, 256, 0, stream>>>(ct, merged);
    gemm_out_k<<<dim3(64,6), 256, 0, stream>>>(merged, WoT, out, rowsum);
    out_time<<<NROWS/256, 256, 0, stream>>>(rowsum, out);
}

// Round 15
// 158.199 us; speedup vs baseline: 1.0126x; 1.0126x over previous
//
#include <hip/hip_runtime.h>
#include <hip/hip_bf16.h>
#include <math.h>

#define HEADS 12
#define NSEQ 1024
#define BATCH 8
#define FDIM 769
#define KP 800                      // padded K dim
#define NROWS (BATCH*NSEQ)          // 8192
#define BH (BATCH*HEADS)            // 96
#define BHROWS (BH*NSEQ)            // 98304

typedef __attribute__((ext_vector_type(8))) short bf16x8_t;
typedef __attribute__((ext_vector_type(4))) short bf16x4_t;
typedef __attribute__((ext_vector_type(4))) float f32x4_t;

__device__ __forceinline__ unsigned short f2bf(float f){
    unsigned u = __float_as_uint(f);
    return (unsigned short)((u + 0x7FFFu + ((u >> 16) & 1u)) >> 16);
}

__device__ __forceinline__ float fast_rcp(float x){
    return __builtin_amdgcn_rcpf(x);
}
__device__ __forceinline__ float fast_exp2(float x){
    return __builtin_amdgcn_exp2f(x);
}

// ---------------- x (8192x769 f32) -> xb (8192x800 bf16, zero pad) ----------------
__global__ __launch_bounds__(256) void conv_x(const float* __restrict__ x, ushort* __restrict__ xb){
    int idx = blockIdx.x*256 + threadIdx.x;          // 8192*200
    int r = idx / 200, c4 = (idx % 200) * 4;
    const float* row = x + (size_t)r * FDIM;
    ushort4 o;
    o.x = (c4+0 < FDIM) ? f2bf(row[c4+0]) : (ushort)0;
    o.y = (c4+1 < FDIM) ? f2bf(row[c4+1]) : (ushort)0;
    o.z = (c4+2 < FDIM) ? f2bf(row[c4+2]) : (ushort)0;
    o.w = (c4+3 < FDIM) ? f2bf(row[c4+3]) : (ushort)0;
    *(ushort4*)(xb + (size_t)r*KP + c4) = o;
}

// ------- W transpose+convert: WcatT[mat*768+n][k]=W[k][n+1]; WoT[n][k']=Wo[perm(k')][n+1] -------
__global__ __launch_bounds__(256) void conv_w(const float* __restrict__ Wq, const float* __restrict__ Wk,
                                              const float* __restrict__ Wv, const float* __restrict__ Wo,
                                              ushort* __restrict__ WcatT, ushort* __restrict__ WoT){
    int kt = blockIdx.x, nt = blockIdx.y, mat = blockIdx.z;
    const float* W = (mat==0)?Wq:(mat==1)?Wk:(mat==2)?Wv:Wo;
    __shared__ float T[32][33];
    int t = threadIdx.x;
    #pragma unroll
    for (int p=0; p<4; p++){
        int idx = t + p*256;
        int kk = idx>>5, nn = idx&31;
        int kp = kt*32 + kk;
        int srck;
        if (mat < 3) srck = (kp < FDIM) ? kp : -1;
        else         srck = (kp < 768) ? kp+1 : ((kp==768) ? 0 : -1);
        T[kk][nn] = (srck >= 0) ? W[(size_t)srck*FDIM + (nt*32+nn) + 1] : 0.0f;
    }
    __syncthreads();
    ushort* outp = (mat < 3) ? (WcatT + (size_t)mat*768*KP) : WoT;
    #pragma unroll
    for (int p=0; p<4; p++){
        int idx = t + p*256;
        int nl = idx>>5, kk = idx&31;
        outp[(size_t)(nt*32+nl)*KP + kt*32 + kk] = f2bf(T[kk][nl]);
    }
}

// ---------------- fused QKV GEMM: xb(8192x800) @ WcatT^T -> head-split bf16 + fp32 times ----------------
__global__ __launch_bounds__(256) void gemm_qkv(const ushort* __restrict__ A, const ushort* __restrict__ Bt,
                                                ushort* __restrict__ qkv, float* __restrict__ tbuf){
    __shared__ __align__(16) ushort As[2][128*32];
    __shared__ __align__(16) ushort Bs[2][128*32];
    const int m0 = blockIdx.x*128, n0 = blockIdx.y*128;
    const int tid = threadIdx.x, lane = tid&63, wave = tid>>6;
    const int wm = wave>>1, wn = wave&1;
    const int g = lane>>4, c = lane&15;

    f32x4_t acc[4][4];
    #pragma unroll
    for (int i=0;i<4;i++)
        #pragma unroll
        for (int j=0;j<4;j++) acc[i][j] = (f32x4_t){0.f,0.f,0.f,0.f};

    bf16x8_t ra[2], rb[2];
    auto LOADS = [&](int kt){
        int k0 = kt*32;
        #pragma unroll
        for (int p=0;p<2;p++){
            int idx = tid + p*256;
            int row = idx>>2, ch = idx&3;
            ra[p] = *(const bf16x8_t*)(A  + (size_t)(m0+row)*KP + k0 + ch*8);
            rb[p] = *(const bf16x8_t*)(Bt + (size_t)(n0+row)*KP + k0 + ch*8);
        }
    };
    auto WRITES = [&](int buf){
        #pragma unroll
        for (int p=0;p<2;p++){
            int idx = tid + p*256;
            int row = idx>>2, ch = idx&3;
            int sw = (ch ^ (row&3))*8;
            *(bf16x8_t*)&As[buf][row*32 + sw] = ra[p];
            *(bf16x8_t*)&Bs[buf][row*32 + sw] = rb[p];
        }
    };

    LOADS(0); WRITES(0); __syncthreads();
    for (int kt=0; kt<25; kt++){
        int cur = kt&1;
        if (kt+1 < 25) LOADS(kt+1);
        bf16x8_t af[4], bf[4];
        #pragma unroll
        for (int mf=0; mf<4; mf++){
            int row = wm*64 + mf*16 + c;
            af[mf] = *(const bf16x8_t*)&As[cur][row*32 + ((g ^ (row&3))*8)];
        }
        #pragma unroll
        for (int nf=0; nf<4; nf++){
            int row = wn*64 + nf*16 + c;
            bf[nf] = *(const bf16x8_t*)&Bs[cur][row*32 + ((g ^ (row&3))*8)];
        }
        #pragma unroll
        for (int mf=0; mf<4; mf++)
            #pragma unroll
            for (int nf=0; nf<4; nf++)
                acc[mf][nf] = __builtin_amdgcn_mfma_f32_16x16x32_bf16(af[mf], bf[nf], acc[mf][nf], 0,0,0);
        if (kt+1 < 25) WRITES(cur^1);
        __syncthreads();
    }

    const int nb = n0 + wn*64;
    const int matv = nb / 768;
    const int hh = (nb % 768) / 64;
    #pragma unroll
    for (int mf=0; mf<4; mf++){
        #pragma unroll
        for (int j=0; j<4; j++){
            int m = m0 + wm*64 + mf*16 + g*4 + j;
            int bb = m >> 10, ns = m & (NSEQ-1);
            size_t rowidx = ((size_t)bb*HEADS + hh)*NSEQ + ns;
            size_t sbase = (size_t)matv*((size_t)BHROWS*64) + rowidx*64;
            float sum = 0.f;
            union { __hip_bfloat162 h2[2]; ushort us[4]; } cv;
            cv.h2[0] = __float22bfloat162_rn(float2{acc[0][0][0], 0.f}); // placeholder init
            #pragma unroll
            for (int nf2=0; nf2<2; nf2++){
                float v0 = acc[mf][nf2*2  ][j];
                float v1 = acc[mf][nf2*2+1][j];
                cv.h2[nf2] = __float22bfloat162_rn(float2{v0, v1});
                sum = fmaf(v0, v0, sum);
                sum = fmaf(v1, v1, sum);
            }
            qkv[sbase +  0 + c] = cv.us[0];
            qkv[sbase + 16 + c] = cv.us[1];
            qkv[sbase + 32 + c] = cv.us[2];
            qkv[sbase + 48 + c] = cv.us[3];
            sum += __shfl_xor(sum,1,64); sum += __shfl_xor(sum,2,64);
            sum += __shfl_xor(sum,4,64); sum += __shfl_xor(sum,8,64);
            if (c == 0) tbuf[(size_t)matv*BHROWS + rowidx] = sqrtf(1.0f + sum);
        }
    }
}

// ---------------- V transpose: vsp[bh][i][d] -> vT[bh][d][i] ----------------
__global__ __launch_bounds__(256) void transpose_v(const ushort* __restrict__ vsp, ushort* __restrict__ vT){
    const int bh = blockIdx.x >> 3, it128 = blockIdx.x & 7;
    __shared__ ushort T2[64*136];                    // [d][128 i + 8 pad]
    const int tid = threadIdx.x;
    {
        int ii = tid>>1, half = tid&1;
        const ushort* src = vsp + ((size_t)bh*NSEQ + it128*128 + ii)*64 + half*32;
        bf16x8_t rr[4];
        #pragma unroll
        for (int p=0;p<4;p++) rr[p] = *(const bf16x8_t*)(src + p*8);
        #pragma unroll
        for (int p=0;p<4;p++)
            #pragma unroll
            for (int e=0;e<8;e++)
                T2[(half*32 + p*8 + e)*136 + ii] = (ushort)rr[p][e];
    }
    __syncthreads();
    {
        int dd = tid>>2, qq = tid&3;
        ushort* dst = vT + ((size_t)bh*64 + dd)*NSEQ + it128*128 + qq*32;
        #pragma unroll
        for (int p=0;p<4;p++)
            *(bf16x8_t*)(dst + p*8) = *(const bf16x8_t*)&T2[dd*136 + qq*32 + p*8];
    }
}

// ---------------- fused Lorentz flash attention (4 waves x 32 j, K=32 PV, sigma-permuted V) ----------------
__global__ __launch_bounds__(256, 3) void lorentz_attn(
    const ushort* __restrict__ qsp, const ushort* __restrict__ ksp, const ushort* __restrict__ vT,
    const float* __restrict__ qtg, const float* __restrict__ ktg, const float* __restrict__ vtg,
    ushort* __restrict__ merged, float* __restrict__ ct)
{
    const int lin = blockIdx.x;
    const int bh = lin % BH;             // same-bh blocks are 96 apart
    const int jt = lin / BH;             // 0..7
    const int b = bh / HEADS, h = bh % HEADS;
    const size_t rb = (size_t)bh * NSEQ;

    // per buffer: Qs 64x64 (4096) | Vt 80x64 (5120) = 9216 ushorts; K-stage unions buf0[0..8191]
    __shared__ __align__(16) ushort QVbuf[2][9216];
    __shared__ __align__(16) float qts[2][64];
    __shared__ __align__(16) float kts[128];

    const int tid = threadIdx.x, lane = tid&63, wave = tid>>6;   // wave 0..3
    const int g = lane>>4, c = lane&15;

    ushort* Kst = &QVbuf[0][0];

    bf16x8_t rq[2], rv[2]; float rqt = 0.f, rvt = 0.f;
    const int sr = tid>>2, sch = tid&3;            // staging: row 0..63, 16-elem chunk 0..3
    auto LOADQV = [&](int it){
        int i0 = it*64;
        const ushort* qp = qsp + (rb + i0 + sr)*64 + sch*16;
        rq[0] = *(const bf16x8_t*)(qp);
        rq[1] = *(const bf16x8_t*)(qp + 8);
        const ushort* vp = vT + ((size_t)bh*64 + sr)*NSEQ + i0 + sch*16;
        rv[0] = *(const bf16x8_t*)(vp);
        rv[1] = *(const bf16x8_t*)(vp + 8);
        if (tid < 64) rqt = qtg[rb + i0 + tid];
        else if (tid < 128) rvt = vtg[rb + i0 + (tid-64)];
    };
    // sigma-permuted V store: position p = ib2*32 + 8*gp + 4*h2 + l holds i = ib2*32 + 16*h2 + 4*gp + l
    auto WRITEQV = [&](int buf){
        ushort* Qb = &QVbuf[buf][0];
        ushort* Vb = &QVbuf[buf][4096];
        *(bf16x8_t*)&Qb[sr*64 + (((2*sch  ) ^ (sr&7))*8)] = rq[0];
        *(bf16x8_t*)&Qb[sr*64 + (((2*sch+1) ^ (sr&7))*8)] = rq[1];
        int pbase = (sch>>1)*32 + (sch&1)*4;       // ib2*32 + 4*h2
        int sx = (sr&7)*8;
        #pragma unroll
        for (int s=0; s<4; s++){
            bf16x4_t sl = (s&1) ? (bf16x4_t)__builtin_shufflevector(rv[s>>1], rv[s>>1], 4,5,6,7)
                                : (bf16x4_t)__builtin_shufflevector(rv[s>>1], rv[s>>1], 0,1,2,3);
            *(bf16x4_t*)&Vb[sr*64 + ((pbase + 8*s) ^ sx)] = sl;
        }
        if (tid < 64) qts[buf][tid] = rqt;
        else if (tid < 128){
            int i = tid - 64;
            int p = 32*(i>>5) + 8*((i>>2)&3) + 4*((i>>4)&1) + (i&3);
            Vb[64*64 + p] = f2bf(rvt);
        }
    };

    // prologue: prefetch tile 0, stage K, zero V pads
    LOADQV(0);
    {
        int row = tid>>1, half = tid&1;
        const ushort* kp = ksp + (rb + jt*128 + row)*64 + half*32;
        #pragma unroll
        for (int p=0; p<4; p++){
            bf16x8_t kr = *(const bf16x8_t*)(kp + p*8);
            int c8 = half*4 + p;
            *(bf16x8_t*)&Kst[row*64 + ((c8 ^ (row&7))*8)] = kr;
        }
    }
    if (tid < 128) kts[tid] = ktg[rb + jt*128 + tid];
    for (int idx = tid; idx < 2*15*64; idx += 256){
        int bz = idx/(15*64), r2 = idx%(15*64);
        QVbuf[bz][4096 + (65 + (r2>>6))*64 + (r2&63)] = 0;
    }
    __syncthreads();

    // hoist K fragments + times (K LDS region dies after this barrier pair)
    bf16x8_t kfrag[2][2]; float kt2e[2];
    #pragma unroll
    for (int jf=0; jf<2; jf++){
        int krow = wave*32 + jf*16 + c;
        kfrag[jf][0] = *(const bf16x8_t*)&Kst[krow*64 + (((  g) ^ (krow&7))*8)];
        kfrag[jf][1] = *(const bf16x8_t*)&Kst[krow*64 + (((4+g) ^ (krow&7))*8)];
        kt2e[jf] = 5.43656365691809f * kts[krow];      // 2e * kt
    }
    __syncthreads();
    WRITEQV(0);
    __syncthreads();

    f32x4_t acc[2][5];
    #pragma unroll
    for (int jf=0; jf<2; jf++)
        #pragma unroll
        for (int dt=0; dt<5; dt++) acc[jf][dt] = (f32x4_t){0.f,0.f,0.f,0.f};

    for (int it=0; it<16; it++){
        int cur = it&1;
        if (it+1 < 16) LOADQV(it+1);
        ushort* Qc = &QVbuf[cur][0];
        ushort* Vc = &QVbuf[cur][4096];
        #pragma unroll
        for (int ib2=0; ib2<2; ib2++){
            // Q fragments for the two 16-row subtiles of this 32-i block
            bf16x8_t qf[2][2];
            #pragma unroll
            for (int t=0; t<2; t++){
                int qrow = ib2*32 + t*16 + c;
                qf[t][0] = *(const bf16x8_t*)&Qc[qrow*64 + (((  g) ^ (qrow&7))*8)];
                qf[t][1] = *(const bf16x8_t*)&Qc[qrow*64 + (((4+g) ^ (qrow&7))*8)];
            }
            f32x4_t qt0 = *(const f32x4_t*)&qts[cur][ib2*32 + g*4];
            f32x4_t qt1 = *(const f32x4_t*)&qts[cur][ib2*32 + 16 + g*4];
            // V fragments: K=32 B-frag, b128 at sigma positions
            bf16x8_t vf[5];
            #pragma unroll
            for (int dt=0; dt<5; dt++){
                int d = dt*16 + c;
                vf[dt] = *(const bf16x8_t*)&Vc[d*64 + ((ib2*32 + g*8) ^ ((d&7)*8))];
            }
            #pragma unroll
            for (int jf=0; jf<2; jf++){
                f32x4_t d0 = (f32x4_t){0.f,0.f,0.f,0.f};
                f32x4_t d1 = (f32x4_t){0.f,0.f,0.f,0.f};
                __builtin_amdgcn_s_setprio(1);
                d0 = __builtin_amdgcn_mfma_f32_16x16x32_bf16(qf[0][0], kfrag[jf][0], d0, 0,0,0);
                d0 = __builtin_amdgcn_mfma_f32_16x16x32_bf16(qf[0][1], kfrag[jf][1], d0, 0,0,0);
                d1 = __builtin_amdgcn_mfma_f32_16x16x32_bf16(qf[1][0], kfrag[jf][0], d1, 0,0,0);
                d1 = __builtin_amdgcn_mfma_f32_16x16x32_bf16(qf[1][1], kfrag[jf][1], d1, 0,0,0);
                __builtin_amdgcn_s_setprio(0);
                // w = exp(1/(1+ln(1+d2))) = exp2(1/(log2(e*(1+d2)) * ln2^2));
                // log2 via exponent bit-hack with 0.48045301 folded into the fma constants
                float w0[4], w1[4];
                #pragma unroll
                for (int r=0; r<4; r++){
                    float c0 = fmaf(qt0[r], kt2e[jf], -2.718281828f);
                    float s0 = fmaf(d0[r], -5.43656365691809f, c0);
                    float L0 = fmaf((float)__float_as_int(s0), 5.727461e-8f, -60.996868f);
                    w0[r] = fast_exp2(fast_rcp(L0));
                    float c1 = fmaf(qt1[r], kt2e[jf], -2.718281828f);
                    float s1 = fmaf(d1[r], -5.43656365691809f, c1);
                    float L1 = fmaf((float)__float_as_int(s1), 5.727461e-8f, -60.996868f);
                    w1[r] = fast_exp2(fast_rcp(L1));
                }
                union { __hip_bfloat162 h2[4]; bf16x8_t v8; } uu;
                uu.h2[0] = __float22bfloat162_rn(float2{w0[0], w0[1]});
                uu.h2[1] = __float22bfloat162_rn(float2{w0[2], w0[3]});
                uu.h2[2] = __float22bfloat162_rn(float2{w1[0], w1[1]});
                uu.h2[3] = __float22bfloat162_rn(float2{w1[2], w1[3]});
                bf16x8_t pa = uu.v8;
                __builtin_amdgcn_s_setprio(1);
                #pragma unroll
                for (int dt=0; dt<5; dt++)
                    acc[jf][dt] = __builtin_amdgcn_mfma_f32_16x16x32_bf16(pa, vf[dt], acc[jf][dt], 0,0,0);
                __builtin_amdgcn_s_setprio(0);
            }
        }
        if (it+1 < 16) WRITEQV(cur^1);
        __syncthreads();
    }

    // centroid normalize + stage output through LDS (reuse buf0 region)
    ushort* Ms = &QVbuf[0][0];
    #pragma unroll
    for (int jf=0; jf<2; jf++){
        #pragma unroll
        for (int r=0; r<4; r++){
            float part = 0.f;
            #pragma unroll
            for (int dt=0; dt<4; dt++) part += acc[jf][dt][r]*acc[jf][dt][r];
            part += __shfl_xor(part,1,64); part += __shfl_xor(part,2,64);
            part += __shfl_xor(part,4,64); part += __shfl_xor(part,8,64);
            float tv = acc[jf][4][r];
            float tb = __shfl(tv, lane & 48, 64);      // c==0 slot holds time accum
            float li = part - tb*tb;
            float f = rsqrtf(fmaxf(fabsf(li), 1e-6f));
            int jl = wave*32 + jf*16 + g*4 + r;
            #pragma unroll
            for (int dt=0; dt<4; dt++)
                Ms[jl*64 + dt*16 + c] = f2bf(acc[jf][dt][r]*f);
            if (c == 0)
                ct[((size_t)b*NSEQ + jt*128 + jl)*HEADS + h] = tb*f;
        }
    }
    __syncthreads();
    {
        int row = tid>>1, half = tid&1;
        size_t gb = ((size_t)b*NSEQ + jt*128 + row)*KP + h*64 + half*32;
        #pragma unroll
        for (int q4=0; q4<4; q4++)
            *(bf16x8_t*)(merged + gb + q4*8) = *(const bf16x8_t*)&Ms[row*64 + half*32 + q4*8];
    }
}

// ---- output GEMM: merged @ WoT^T -> out[:,1:769] fp32, + per-row partial sum-of-squares ----
__global__ __launch_bounds__(256) void gemm_out_k(const ushort* __restrict__ A, const ushort* __restrict__ Bt,
                                                  float* __restrict__ out, float* __restrict__ rowsum){
    __shared__ __align__(16) ushort As[2][128*32];
    __shared__ __align__(16) ushort Bs[2][128*32];
    const int m0 = blockIdx.x*128, n0 = blockIdx.y*128;
    const int tid = threadIdx.x, lane = tid&63, wave = tid>>6;
    const int wm = wave>>1, wn = wave&1;
    const int g = lane>>4, c = lane&15;

    f32x4_t acc[4][4];
    #pragma unroll
    for (int i=0;i<4;i++)
        #pragma unroll
        for (int j=0;j<4;j++) acc[i][j] = (f32x4_t){0.f,0.f,0.f,0.f};

    bf16x8_t ra[2], rb[2];
    auto LOADS = [&](int kt){
        int k0 = kt*32;
        #pragma unroll
        for (int p=0;p<2;p++){
            int idx = tid + p*256;
            int row = idx>>2, ch = idx&3;
            ra[p] = *(const bf16x8_t*)(A  + (size_t)(m0+row)*KP + k0 + ch*8);
            rb[p] = *(const bf16x8_t*)(Bt + (size_t)(n0+row)*KP + k0 + ch*8);
        }
    };
    auto WRITES = [&](int buf){
        #pragma unroll
        for (int p=0;p<2;p++){
            int idx = tid + p*256;
            int row = idx>>2, ch = idx&3;
            int sw = (ch ^ (row&3))*8;
            *(bf16x8_t*)&As[buf][row*32 + sw] = ra[p];
            *(bf16x8_t*)&Bs[buf][row*32 + sw] = rb[p];
        }
    };

    LOADS(0); WRITES(0); __syncthreads();
    for (int kt=0; kt<25; kt++){
        int cur = kt&1;
        if (kt+1 < 25) LOADS(kt+1);
        bf16x8_t af[4], bf[4];
        #pragma unroll
        for (int mf=0; mf<4; mf++){
            int row = wm*64 + mf*16 + c;
            af[mf] = *(const bf16x8_t*)&As[cur][row*32 + ((g ^ (row&3))*8)];
        }
        #pragma unroll
        for (int nf=0; nf<4; nf++){
            int row = wn*64 + nf*16 + c;
            bf[nf] = *(const bf16x8_t*)&Bs[cur][row*32 + ((g ^ (row&3))*8)];
        }
        #pragma unroll
        for (int mf=0; mf<4; mf++)
            #pragma unroll
            for (int nf=0; nf<4; nf++)
                acc[mf][nf] = __builtin_amdgcn_mfma_f32_16x16x32_bf16(af[mf], bf[nf], acc[mf][nf], 0,0,0);
        if (kt+1 < 25) WRITES(cur^1);
        __syncthreads();
    }

    const int slot = blockIdx.y*2 + wn;              // 0..11
    #pragma unroll
    for (int mf=0; mf<4; mf++){
        #pragma unroll
        for (int j=0; j<4; j++){
            int m = m0 + wm*64 + mf*16 + g*4 + j;
            float s = 0.f;
            #pragma unroll
            for (int nf=0; nf<4; nf++){
                float v = acc[mf][nf][j];
                out[(size_t)m*FDIM + 1 + n0 + wn*64 + nf*16 + c] = v;
                s = fmaf(v, v, s);
            }
            s += __shfl_xor(s,1,64); s += __shfl_xor(s,2,64);
            s += __shfl_xor(s,4,64); s += __shfl_xor(s,8,64);
            if (c == 0) rowsum[(size_t)slot*NROWS + m] = s;
        }
    }
}

// ------- merged[:,768(time)] = sqrt(max(sum_h ct^2 - 11, eps)); zero cols 769..799 -------
__global__ __launch_bounds__(256) void time_r_k(const float* __restrict__ ct, ushort* __restrict__ merged){
    int r = blockIdx.x*256 + threadIdx.x;
    float s = 0.f;
    #pragma unroll
    for (int hh=0; hh<HEADS; hh++){
        float t = ct[(size_t)r*HEADS + hh];
        s = fmaf(t, t, s);
    }
    bf16x8_t z = (bf16x8_t){0,0,0,0,0,0,0,0};
    bf16x8_t z0 = z;
    z0[0] = (short)f2bf(sqrtf(fmaxf(s - (float)(HEADS-1), 1e-6f)));
    ushort* dst = merged + (size_t)r*KP + 768;       // 16B aligned (1600r+1536)
    *(bf16x8_t*)(dst)      = z0;
    *(bf16x8_t*)(dst + 8)  = z;
    *(bf16x8_t*)(dst + 16) = z;
    *(bf16x8_t*)(dst + 24) = z;
}

// ---------------- out[:,0] = sqrt(1 + sum over 12 rowsum slots) ----------------
__global__ __launch_bounds__(256) void out_time(const float* __restrict__ rowsum, float* __restrict__ out)
{
    int r = blockIdx.x*256 + threadIdx.x;
    float s = 1.0f;
    #pragma unroll
    for (int k=0; k<12; k++) s += rowsum[(size_t)k*NROWS + r];
    out[(size_t)r*FDIM] = sqrtf(s);
}

extern "C" void kernel_launch(void* const* d_in, const int* in_sizes, int n_in,
                              void* d_out, int out_size, void* d_ws, size_t ws_size,
                              hipStream_t stream)
{
    const float* x  = (const float*)d_in[0];
    const float* Wq = (const float*)d_in[1];
    const float* Wk = (const float*)d_in[2];
    const float* Wv = (const float*)d_in[3];
    const float* Wo = (const float*)d_in[4];
    float* out = (float*)d_out;

    char* p = (char*)d_ws;
    ushort* xb     = (ushort*)p; p += (size_t)NROWS*KP*2;          // 13.1 MB
    ushort* WcatT  = (ushort*)p; p += (size_t)2304*KP*2;           //  3.7 MB
    ushort* WoT    = (ushort*)p; p += (size_t)768*KP*2;            //  1.2 MB
    ushort* qkv    = (ushort*)p; p += (size_t)3*BHROWS*64*2;       // 37.7 MB
    float*  tbuf   = (float*)p;  p += (size_t)3*BHROWS*4;          //  1.2 MB
    float*  ct     = (float*)p;  p += (size_t)NROWS*HEADS*4;       //  0.4 MB
    ushort* merged = (ushort*)p; p += (size_t)NROWS*KP*2;          // 13.1 MB
    ushort* vT     = (ushort*)p; p += (size_t)BH*64*NSEQ*2;        // 12.6 MB
    float*  rowsum = (float*)p;  p += (size_t)12*NROWS*4;          //  0.4 MB

    const size_t SP = (size_t)BHROWS*64;

    conv_x<<<6400, 256, 0, stream>>>(x, xb);
    conv_w<<<dim3(25,24,4), 256, 0, stream>>>(Wq, Wk, Wv, Wo, WcatT, WoT);
    gemm_qkv<<<dim3(64,18), 256, 0, stream>>>(xb, WcatT, qkv, tbuf);
    transpose_v<<<768, 256, 0, stream>>>(qkv + 2*SP, vT);
    lorentz_attn<<<768, 256, 0, stream>>>(qkv, qkv + SP, vT,
                                          tbuf, tbuf + BHROWS, tbuf + 2*BHROWS,
                                          merged, ct);
    time_r_k<<<NROWS/256, 256, 0, stream>>>(ct, merged);
    gemm_out_k<<<dim3(64,6), 256, 0, stream>>>(merged, WoT, out, rowsum);
    out_time<<<NROWS/256, 256, 0, stream>>>(rowsum, out);
}

// Round 16
// 149.025 us; speedup vs baseline: 1.0749x; 1.0616x over previous
//
#include <hip/hip_runtime.h>
#include <hip/hip_bf16.h>
#include <math.h>

#define HEADS 12
#define NSEQ 1024
#define BATCH 8
#define FDIM 769
#define KP 800                      // padded K dim
#define NROWS (BATCH*NSEQ)          // 8192
#define BH (BATCH*HEADS)            // 96
#define BHROWS (BH*NSEQ)            // 98304

typedef __attribute__((ext_vector_type(8))) short bf16x8_t;
typedef __attribute__((ext_vector_type(4))) short bf16x4_t;
typedef __attribute__((ext_vector_type(4))) float f32x4_t;

__device__ __forceinline__ unsigned short f2bf(float f){
    unsigned u = __float_as_uint(f);
    return (unsigned short)((u + 0x7FFFu + ((u >> 16) & 1u)) >> 16);
}
__device__ __forceinline__ float bf2f(ushort u){
    return __uint_as_float(((unsigned)u) << 16);
}

__device__ __forceinline__ float fast_rcp(float x){
    return __builtin_amdgcn_rcpf(x);
}
__device__ __forceinline__ float fast_exp2(float x){
    return __builtin_amdgcn_exp2f(x);
}

// ---------------- x (8192x769 f32) -> xb (8192x800 bf16, zero pad) ----------------
__global__ __launch_bounds__(256) void conv_x(const float* __restrict__ x, ushort* __restrict__ xb){
    int idx = blockIdx.x*256 + threadIdx.x;          // 8192*200
    int r = idx / 200, c4 = (idx % 200) * 4;
    const float* row = x + (size_t)r * FDIM;
    ushort4 o;
    o.x = (c4+0 < FDIM) ? f2bf(row[c4+0]) : (ushort)0;
    o.y = (c4+1 < FDIM) ? f2bf(row[c4+1]) : (ushort)0;
    o.z = (c4+2 < FDIM) ? f2bf(row[c4+2]) : (ushort)0;
    o.w = (c4+3 < FDIM) ? f2bf(row[c4+3]) : (ushort)0;
    *(ushort4*)(xb + (size_t)r*KP + c4) = o;
}

// ------- W transpose+convert: WcatT[mat*768+n][k]=W[k][n+1]; WoT[n][k']=Wo[perm(k')][n+1] -------
__global__ __launch_bounds__(256) void conv_w(const float* __restrict__ Wq, const float* __restrict__ Wk,
                                              const float* __restrict__ Wv, const float* __restrict__ Wo,
                                              ushort* __restrict__ WcatT, ushort* __restrict__ WoT){
    int kt = blockIdx.x, nt = blockIdx.y, mat = blockIdx.z;
    const float* W = (mat==0)?Wq:(mat==1)?Wk:(mat==2)?Wv:Wo;
    __shared__ float T[32][33];
    int t = threadIdx.x;
    #pragma unroll
    for (int p=0; p<4; p++){
        int idx = t + p*256;
        int kk = idx>>5, nn = idx&31;
        int kp = kt*32 + kk;
        int srck;
        if (mat < 3) srck = (kp < FDIM) ? kp : -1;
        else         srck = (kp < 768) ? kp+1 : ((kp==768) ? 0 : -1);
        T[kk][nn] = (srck >= 0) ? W[(size_t)srck*FDIM + (nt*32+nn) + 1] : 0.0f;
    }
    __syncthreads();
    ushort* outp = (mat < 3) ? (WcatT + (size_t)mat*768*KP) : WoT;
    #pragma unroll
    for (int p=0; p<4; p++){
        int idx = t + p*256;
        int nl = idx>>5, kk = idx&31;
        outp[(size_t)(nt*32+nl)*KP + kt*32 + kk] = f2bf(T[kk][nl]);
    }
}

// ---------------- fused QKV GEMM: xb(8192x800) @ WcatT^T -> head-split bf16 + fp32 times ----------------
// 24 MFMA K-tiles (K=768) + fp32 rank-1 epilogue for the k=768 column (769..799 are zero pad)
__global__ __launch_bounds__(256) void gemm_qkv(const ushort* __restrict__ A, const ushort* __restrict__ Bt,
                                                ushort* __restrict__ qkv, float* __restrict__ tbuf){
    __shared__ __align__(16) ushort As[2][128*32];
    __shared__ __align__(16) ushort Bs[2][128*32];
    const int m0 = blockIdx.x*128, n0 = blockIdx.y*128;
    const int tid = threadIdx.x, lane = tid&63, wave = tid>>6;
    const int wm = wave>>1, wn = wave&1;
    const int g = lane>>4, c = lane&15;

    f32x4_t acc[4][4];
    #pragma unroll
    for (int i=0;i<4;i++)
        #pragma unroll
        for (int j=0;j<4;j++) acc[i][j] = (f32x4_t){0.f,0.f,0.f,0.f};

    bf16x8_t ra[2], rb[2];
    auto LOADS = [&](int kt){
        int k0 = kt*32;
        #pragma unroll
        for (int p=0;p<2;p++){
            int idx = tid + p*256;
            int row = idx>>2, ch = idx&3;
            ra[p] = *(const bf16x8_t*)(A  + (size_t)(m0+row)*KP + k0 + ch*8);
            rb[p] = *(const bf16x8_t*)(Bt + (size_t)(n0+row)*KP + k0 + ch*8);
        }
    };
    auto WRITES = [&](int buf){
        #pragma unroll
        for (int p=0;p<2;p++){
            int idx = tid + p*256;
            int row = idx>>2, ch = idx&3;
            int sw = (ch ^ (row&3))*8;
            *(bf16x8_t*)&As[buf][row*32 + sw] = ra[p];
            *(bf16x8_t*)&Bs[buf][row*32 + sw] = rb[p];
        }
    };

    LOADS(0); WRITES(0); __syncthreads();
    for (int kt=0; kt<24; kt++){
        int cur = kt&1;
        if (kt+1 < 24) LOADS(kt+1);
        bf16x8_t af[4], bf[4];
        #pragma unroll
        for (int mf=0; mf<4; mf++){
            int row = wm*64 + mf*16 + c;
            af[mf] = *(const bf16x8_t*)&As[cur][row*32 + ((g ^ (row&3))*8)];
        }
        #pragma unroll
        for (int nf=0; nf<4; nf++){
            int row = wn*64 + nf*16 + c;
            bf[nf] = *(const bf16x8_t*)&Bs[cur][row*32 + ((g ^ (row&3))*8)];
        }
        #pragma unroll
        for (int mf=0; mf<4; mf++)
            #pragma unroll
            for (int nf=0; nf<4; nf++)
                acc[mf][nf] = __builtin_amdgcn_mfma_f32_16x16x32_bf16(af[mf], bf[nf], acc[mf][nf], 0,0,0);
        if (kt+1 < 24) WRITES(cur^1);
        __syncthreads();
    }

    // rank-1 update for k=768 (last real column; loop covered k<768)
    {
        ushort* Acol = &As[0][0];
        ushort* Bcol = &Bs[0][0];
        if (tid < 128) Acol[tid] = A[(size_t)(m0+tid)*KP + 768];
        else           Bcol[tid-128] = Bt[(size_t)(n0+tid-128)*KP + 768];
        __syncthreads();
        float bv4[4];
        #pragma unroll
        for (int nf=0; nf<4; nf++) bv4[nf] = bf2f(Bcol[wn*64 + nf*16 + c]);
        #pragma unroll
        for (int mf=0; mf<4; mf++){
            #pragma unroll
            for (int j=0; j<4; j++){
                float a = bf2f(Acol[wm*64 + mf*16 + g*4 + j]);
                #pragma unroll
                for (int nf=0; nf<4; nf++)
                    acc[mf][nf][j] = fmaf(a, bv4[nf], acc[mf][nf][j]);
            }
        }
    }

    const int nb = n0 + wn*64;
    const int matv = nb / 768;
    const int hh = (nb % 768) / 64;
    #pragma unroll
    for (int mf=0; mf<4; mf++){
        #pragma unroll
        for (int j=0; j<4; j++){
            int m = m0 + wm*64 + mf*16 + g*4 + j;
            int bb = m >> 10, ns = m & (NSEQ-1);
            size_t rowidx = ((size_t)bb*HEADS + hh)*NSEQ + ns;
            size_t sbase = (size_t)matv*((size_t)BHROWS*64) + rowidx*64;
            float sum = 0.f;
            union { __hip_bfloat162 h2[2]; ushort us[4]; } cv;
            #pragma unroll
            for (int nf2=0; nf2<2; nf2++){
                float v0 = acc[mf][nf2*2  ][j];
                float v1 = acc[mf][nf2*2+1][j];
                cv.h2[nf2] = __float22bfloat162_rn(float2{v0, v1});
                sum = fmaf(v0, v0, sum);
                sum = fmaf(v1, v1, sum);
            }
            qkv[sbase +  0 + c] = cv.us[0];
            qkv[sbase + 16 + c] = cv.us[1];
            qkv[sbase + 32 + c] = cv.us[2];
            qkv[sbase + 48 + c] = cv.us[3];
            sum += __shfl_xor(sum,1,64); sum += __shfl_xor(sum,2,64);
            sum += __shfl_xor(sum,4,64); sum += __shfl_xor(sum,8,64);
            if (c == 0) tbuf[(size_t)matv*BHROWS + rowidx] = sqrtf(1.0f + sum);
        }
    }
}

// ---------------- V transpose: vsp[bh][i][d] -> vT[bh][d][i] ----------------
__global__ __launch_bounds__(256) void transpose_v(const ushort* __restrict__ vsp, ushort* __restrict__ vT){
    const int bh = blockIdx.x >> 3, it128 = blockIdx.x & 7;
    __shared__ ushort T2[64*136];                    // [d][128 i + 8 pad]
    const int tid = threadIdx.x;
    {
        int ii = tid>>1, half = tid&1;
        const ushort* src = vsp + ((size_t)bh*NSEQ + it128*128 + ii)*64 + half*32;
        bf16x8_t rr[4];
        #pragma unroll
        for (int p=0;p<4;p++) rr[p] = *(const bf16x8_t*)(src + p*8);
        #pragma unroll
        for (int p=0;p<4;p++)
            #pragma unroll
            for (int e=0;e<8;e++)
                T2[(half*32 + p*8 + e)*136 + ii] = (ushort)rr[p][e];
    }
    __syncthreads();
    {
        int dd = tid>>2, qq = tid&3;
        ushort* dst = vT + ((size_t)bh*64 + dd)*NSEQ + it128*128 + qq*32;
        #pragma unroll
        for (int p=0;p<4;p++)
            *(bf16x8_t*)(dst + p*8) = *(const bf16x8_t*)&T2[dd*136 + qq*32 + p*8];
    }
}

// ---------------- fused Lorentz flash attention (4 waves x 32 j, K=32 PV, sigma-permuted V) ----------------
__global__ __launch_bounds__(256, 3) void lorentz_attn(
    const ushort* __restrict__ qsp, const ushort* __restrict__ ksp, const ushort* __restrict__ vT,
    const float* __restrict__ qtg, const float* __restrict__ ktg, const float* __restrict__ vtg,
    ushort* __restrict__ merged, float* __restrict__ ct)
{
    const int lin = blockIdx.x;
    const int bh = lin % BH;             // same-bh blocks are 96 apart
    const int jt = lin / BH;             // 0..7
    const int b = bh / HEADS, h = bh % HEADS;
    const size_t rb = (size_t)bh * NSEQ;

    // per buffer: Qs 64x64 (4096) | Vt 80x64 (5120) = 9216 ushorts; K-stage unions buf0[0..8191]
    __shared__ __align__(16) ushort QVbuf[2][9216];
    __shared__ __align__(16) float qts[2][64];
    __shared__ __align__(16) float kts[128];

    const int tid = threadIdx.x, lane = tid&63, wave = tid>>6;   // wave 0..3
    const int g = lane>>4, c = lane&15;

    ushort* Kst = &QVbuf[0][0];

    bf16x8_t rq[2], rv[2]; float rqt = 0.f, rvt = 0.f;
    const int sr = tid>>2, sch = tid&3;            // staging: row 0..63, 16-elem chunk 0..3
    auto LOADQV = [&](int it){
        int i0 = it*64;
        const ushort* qp = qsp + (rb + i0 + sr)*64 + sch*16;
        rq[0] = *(const bf16x8_t*)(qp);
        rq[1] = *(const bf16x8_t*)(qp + 8);
        const ushort* vp = vT + ((size_t)bh*64 + sr)*NSEQ + i0 + sch*16;
        rv[0] = *(const bf16x8_t*)(vp);
        rv[1] = *(const bf16x8_t*)(vp + 8);
        if (tid < 64) rqt = qtg[rb + i0 + tid];
        else if (tid < 128) rvt = vtg[rb + i0 + (tid-64)];
    };
    // sigma-permuted V store: position p = ib2*32 + 8*gp + 4*h2 + l holds i = ib2*32 + 16*h2 + 4*gp + l
    auto WRITEQV = [&](int buf){
        ushort* Qb = &QVbuf[buf][0];
        ushort* Vb = &QVbuf[buf][4096];
        *(bf16x8_t*)&Qb[sr*64 + (((2*sch  ) ^ (sr&7))*8)] = rq[0];
        *(bf16x8_t*)&Qb[sr*64 + (((2*sch+1) ^ (sr&7))*8)] = rq[1];
        int pbase = (sch>>1)*32 + (sch&1)*4;       // ib2*32 + 4*h2
        int sx = (sr&7)*8;
        #pragma unroll
        for (int s=0; s<4; s++){
            bf16x4_t sl = (s&1) ? (bf16x4_t)__builtin_shufflevector(rv[s>>1], rv[s>>1], 4,5,6,7)
                                : (bf16x4_t)__builtin_shufflevector(rv[s>>1], rv[s>>1], 0,1,2,3);
            *(bf16x4_t*)&Vb[sr*64 + ((pbase + 8*s) ^ sx)] = sl;
        }
        if (tid < 64) qts[buf][tid] = rqt;
        else if (tid < 128){
            int i = tid - 64;
            int p = 32*(i>>5) + 8*((i>>2)&3) + 4*((i>>4)&1) + (i&3);
            Vb[64*64 + p] = f2bf(rvt);
        }
    };

    // prologue: prefetch tile 0, stage K, zero V pads
    LOADQV(0);
    {
        int row = tid>>1, half = tid&1;
        const ushort* kp = ksp + (rb + jt*128 + row)*64 + half*32;
        #pragma unroll
        for (int p=0; p<4; p++){
            bf16x8_t kr = *(const bf16x8_t*)(kp + p*8);
            int c8 = half*4 + p;
            *(bf16x8_t*)&Kst[row*64 + ((c8 ^ (row&7))*8)] = kr;
        }
    }
    if (tid < 128) kts[tid] = ktg[rb + jt*128 + tid];
    for (int idx = tid; idx < 2*15*64; idx += 256){
        int bz = idx/(15*64), r2 = idx%(15*64);
        QVbuf[bz][4096 + (65 + (r2>>6))*64 + (r2&63)] = 0;
    }
    __syncthreads();

    // hoist K fragments + times (K LDS region dies after this barrier pair)
    bf16x8_t kfrag[2][2]; float kt2e[2];
    #pragma unroll
    for (int jf=0; jf<2; jf++){
        int krow = wave*32 + jf*16 + c;
        kfrag[jf][0] = *(const bf16x8_t*)&Kst[krow*64 + (((  g) ^ (krow&7))*8)];
        kfrag[jf][1] = *(const bf16x8_t*)&Kst[krow*64 + (((4+g) ^ (krow&7))*8)];
        kt2e[jf] = 5.43656365691809f * kts[krow];      // 2e * kt
    }
    __syncthreads();
    WRITEQV(0);
    __syncthreads();

    f32x4_t acc[2][5];
    #pragma unroll
    for (int jf=0; jf<2; jf++)
        #pragma unroll
        for (int dt=0; dt<5; dt++) acc[jf][dt] = (f32x4_t){0.f,0.f,0.f,0.f};

    for (int it=0; it<16; it++){
        int cur = it&1;
        if (it+1 < 16) LOADQV(it+1);
        ushort* Qc = &QVbuf[cur][0];
        ushort* Vc = &QVbuf[cur][4096];
        #pragma unroll
        for (int ib2=0; ib2<2; ib2++){
            // Q fragments for the two 16-row subtiles of this 32-i block
            bf16x8_t qf[2][2];
            #pragma unroll
            for (int t=0; t<2; t++){
                int qrow = ib2*32 + t*16 + c;
                qf[t][0] = *(const bf16x8_t*)&Qc[qrow*64 + (((  g) ^ (qrow&7))*8)];
                qf[t][1] = *(const bf16x8_t*)&Qc[qrow*64 + (((4+g) ^ (qrow&7))*8)];
            }
            f32x4_t qt0 = *(const f32x4_t*)&qts[cur][ib2*32 + g*4];
            f32x4_t qt1 = *(const f32x4_t*)&qts[cur][ib2*32 + 16 + g*4];
            // V fragments: K=32 B-frag, b128 at sigma positions
            bf16x8_t vf[5];
            #pragma unroll
            for (int dt=0; dt<5; dt++){
                int d = dt*16 + c;
                vf[dt] = *(const bf16x8_t*)&Vc[d*64 + ((ib2*32 + g*8) ^ ((d&7)*8))];
            }
            #pragma unroll
            for (int jf=0; jf<2; jf++){
                f32x4_t d0 = (f32x4_t){0.f,0.f,0.f,0.f};
                f32x4_t d1 = (f32x4_t){0.f,0.f,0.f,0.f};
                __builtin_amdgcn_s_setprio(1);
                d0 = __builtin_amdgcn_mfma_f32_16x16x32_bf16(qf[0][0], kfrag[jf][0], d0, 0,0,0);
                d0 = __builtin_amdgcn_mfma_f32_16x16x32_bf16(qf[0][1], kfrag[jf][1], d0, 0,0,0);
                d1 = __builtin_amdgcn_mfma_f32_16x16x32_bf16(qf[1][0], kfrag[jf][0], d1, 0,0,0);
                d1 = __builtin_amdgcn_mfma_f32_16x16x32_bf16(qf[1][1], kfrag[jf][1], d1, 0,0,0);
                __builtin_amdgcn_s_setprio(0);
                // w = exp(1/(1+ln(1+d2))) = exp2(1/(log2(e*(1+d2)) * ln2^2));
                // log2 via exponent bit-hack with 0.48045301 folded into the fma constants
                float w0[4], w1[4];
                #pragma unroll
                for (int r=0; r<4; r++){
                    float c0 = fmaf(qt0[r], kt2e[jf], -2.718281828f);
                    float s0 = fmaf(d0[r], -5.43656365691809f, c0);
                    float L0 = fmaf((float)__float_as_int(s0), 5.727461e-8f, -60.996868f);
                    w0[r] = fast_exp2(fast_rcp(L0));
                    float c1 = fmaf(qt1[r], kt2e[jf], -2.718281828f);
                    float s1 = fmaf(d1[r], -5.43656365691809f, c1);
                    float L1 = fmaf((float)__float_as_int(s1), 5.727461e-8f, -60.996868f);
                    w1[r] = fast_exp2(fast_rcp(L1));
                }
                union { __hip_bfloat162 h2[4]; bf16x8_t v8; } uu;
                uu.h2[0] = __float22bfloat162_rn(float2{w0[0], w0[1]});
                uu.h2[1] = __float22bfloat162_rn(float2{w0[2], w0[3]});
                uu.h2[2] = __float22bfloat162_rn(float2{w1[0], w1[1]});
                uu.h2[3] = __float22bfloat162_rn(float2{w1[2], w1[3]});
                bf16x8_t pa = uu.v8;
                __builtin_amdgcn_s_setprio(1);
                #pragma unroll
                for (int dt=0; dt<5; dt++)
                    acc[jf][dt] = __builtin_amdgcn_mfma_f32_16x16x32_bf16(pa, vf[dt], acc[jf][dt], 0,0,0);
                __builtin_amdgcn_s_setprio(0);
            }
        }
        if (it+1 < 16) WRITEQV(cur^1);
        __syncthreads();
    }

    // centroid normalize + stage output through LDS (reuse buf0 region)
    ushort* Ms = &QVbuf[0][0];
    #pragma unroll
    for (int jf=0; jf<2; jf++){
        #pragma unroll
        for (int r=0; r<4; r++){
            float part = 0.f;
            #pragma unroll
            for (int dt=0; dt<4; dt++) part += acc[jf][dt][r]*acc[jf][dt][r];
            part += __shfl_xor(part,1,64); part += __shfl_xor(part,2,64);
            part += __shfl_xor(part,4,64); part += __shfl_xor(part,8,64);
            float tv = acc[jf][4][r];
            float tb = __shfl(tv, lane & 48, 64);      // c==0 slot holds time accum
            float li = part - tb*tb;
            float f = rsqrtf(fmaxf(fabsf(li), 1e-6f));
            int jl = wave*32 + jf*16 + g*4 + r;
            #pragma unroll
            for (int dt=0; dt<4; dt++)
                Ms[jl*64 + dt*16 + c] = f2bf(acc[jf][dt][r]*f);
            if (c == 0)
                ct[((size_t)b*NSEQ + jt*128 + jl)*HEADS + h] = tb*f;
        }
    }
    __syncthreads();
    {
        int row = tid>>1, half = tid&1;
        size_t gb = ((size_t)b*NSEQ + jt*128 + row)*KP + h*64 + half*32;
        #pragma unroll
        for (int q4=0; q4<4; q4++)
            *(bf16x8_t*)(merged + gb + q4*8) = *(const bf16x8_t*)&Ms[row*64 + half*32 + q4*8];
    }
}

// ---- output GEMM: merged @ WoT^T -> out[:,1:769] fp32, + per-row partial sum-of-squares ----
// 24 MFMA K-tiles + fp32 rank-1 epilogue for k'=768 (time column)
__global__ __launch_bounds__(256) void gemm_out_k(const ushort* __restrict__ A, const ushort* __restrict__ Bt,
                                                  float* __restrict__ out, float* __restrict__ rowsum){
    __shared__ __align__(16) ushort As[2][128*32];
    __shared__ __align__(16) ushort Bs[2][128*32];
    const int m0 = blockIdx.x*128, n0 = blockIdx.y*128;
    const int tid = threadIdx.x, lane = tid&63, wave = tid>>6;
    const int wm = wave>>1, wn = wave&1;
    const int g = lane>>4, c = lane&15;

    f32x4_t acc[4][4];
    #pragma unroll
    for (int i=0;i<4;i++)
        #pragma unroll
        for (int j=0;j<4;j++) acc[i][j] = (f32x4_t){0.f,0.f,0.f,0.f};

    bf16x8_t ra[2], rb[2];
    auto LOADS = [&](int kt){
        int k0 = kt*32;
        #pragma unroll
        for (int p=0;p<2;p++){
            int idx = tid + p*256;
            int row = idx>>2, ch = idx&3;
            ra[p] = *(const bf16x8_t*)(A  + (size_t)(m0+row)*KP + k0 + ch*8);
            rb[p] = *(const bf16x8_t*)(Bt + (size_t)(n0+row)*KP + k0 + ch*8);
        }
    };
    auto WRITES = [&](int buf){
        #pragma unroll
        for (int p=0;p<2;p++){
            int idx = tid + p*256;
            int row = idx>>2, ch = idx&3;
            int sw = (ch ^ (row&3))*8;
            *(bf16x8_t*)&As[buf][row*32 + sw] = ra[p];
            *(bf16x8_t*)&Bs[buf][row*32 + sw] = rb[p];
        }
    };

    LOADS(0); WRITES(0); __syncthreads();
    for (int kt=0; kt<24; kt++){
        int cur = kt&1;
        if (kt+1 < 24) LOADS(kt+1);
        bf16x8_t af[4], bf[4];
        #pragma unroll
        for (int mf=0; mf<4; mf++){
            int row = wm*64 + mf*16 + c;
            af[mf] = *(const bf16x8_t*)&As[cur][row*32 + ((g ^ (row&3))*8)];
        }
        #pragma unroll
        for (int nf=0; nf<4; nf++){
            int row = wn*64 + nf*16 + c;
            bf[nf] = *(const bf16x8_t*)&Bs[cur][row*32 + ((g ^ (row&3))*8)];
        }
        #pragma unroll
        for (int mf=0; mf<4; mf++)
            #pragma unroll
            for (int nf=0; nf<4; nf++)
                acc[mf][nf] = __builtin_amdgcn_mfma_f32_16x16x32_bf16(af[mf], bf[nf], acc[mf][nf], 0,0,0);
        if (kt+1 < 24) WRITES(cur^1);
        __syncthreads();
    }

    // rank-1 update for k'=768 (time column)
    {
        ushort* Acol = &As[0][0];
        ushort* Bcol = &Bs[0][0];
        if (tid < 128) Acol[tid] = A[(size_t)(m0+tid)*KP + 768];
        else           Bcol[tid-128] = Bt[(size_t)(n0+tid-128)*KP + 768];
        __syncthreads();
        float bv4[4];
        #pragma unroll
        for (int nf=0; nf<4; nf++) bv4[nf] = bf2f(Bcol[wn*64 + nf*16 + c]);
        #pragma unroll
        for (int mf=0; mf<4; mf++){
            #pragma unroll
            for (int j=0; j<4; j++){
                float a = bf2f(Acol[wm*64 + mf*16 + g*4 + j]);
                #pragma unroll
                for (int nf=0; nf<4; nf++)
                    acc[mf][nf][j] = fmaf(a, bv4[nf], acc[mf][nf][j]);
            }
        }
    }

    const int slot = blockIdx.y*2 + wn;              // 0..11
    #pragma unroll
    for (int mf=0; mf<4; mf++){
        #pragma unroll
        for (int j=0; j<4; j++){
            int m = m0 + wm*64 + mf*16 + g*4 + j;
            float s = 0.f;
            #pragma unroll
            for (int nf=0; nf<4; nf++){
                float v = acc[mf][nf][j];
                out[(size_t)m*FDIM + 1 + n0 + wn*64 + nf*16 + c] = v;
                s = fmaf(v, v, s);
            }
            s += __shfl_xor(s,1,64); s += __shfl_xor(s,2,64);
            s += __shfl_xor(s,4,64); s += __shfl_xor(s,8,64);
            if (c == 0) rowsum[(size_t)slot*NROWS + m] = s;
        }
    }
}

// ------- merged[:,768(time)] = sqrt(max(sum_h ct^2 - 11, eps)); zero cols 769..799 -------
__global__ __launch_bounds__(256) void time_r_k(const float* __restrict__ ct, ushort* __restrict__ merged){
    int r = blockIdx.x*256 + threadIdx.x;
    float s = 0.f;
    #pragma unroll
    for (int hh=0; hh<HEADS; hh++){
        float t = ct[(size_t)r*HEADS + hh];
        s = fmaf(t, t, s);
    }
    bf16x8_t z = (bf16x8_t){0,0,0,0,0,0,0,0};
    bf16x8_t z0 = z;
    z0[0] = (short)f2bf(sqrtf(fmaxf(s - (float)(HEADS-1), 1e-6f)));
    ushort* dst = merged + (size_t)r*KP + 768;       // 16B aligned (1600r+1536)
    *(bf16x8_t*)(dst)      = z0;
    *(bf16x8_t*)(dst + 8)  = z;
    *(bf16x8_t*)(dst + 16) = z;
    *(bf16x8_t*)(dst + 24) = z;
}

// ---------------- out[:,0] = sqrt(1 + sum over 12 rowsum slots) ----------------
__global__ __launch_bounds__(256) void out_time(const float* __restrict__ rowsum, float* __restrict__ out)
{
    int r = blockIdx.x*256 + threadIdx.x;
    float s = 1.0f;
    #pragma unroll
    for (int k=0; k<12; k++) s += rowsum[(size_t)k*NROWS + r];
    out[(size_t)r*FDIM] = sqrtf(s);
}

extern "C" void kernel_launch(void* const* d_in, const int* in_sizes, int n_in,
                              void* d_out, int out_size, void* d_ws, size_t ws_size,
                              hipStream_t stream)
{
    const float* x  = (const float*)d_in[0];
    const float* Wq = (const float*)d_in[1];
    const float* Wk = (const float*)d_in[2];
    const float* Wv = (const float*)d_in[3];
    const float* Wo = (const float*)d_in[4];
    float* out = (float*)d_out;

    char* p = (char*)d_ws;
    ushort* xb     = (ushort*)p; p += (size_t)NROWS*KP*2;          // 13.1 MB
    ushort* WcatT  = (ushort*)p; p += (size_t)2304*KP*2;           //  3.7 MB
    ushort* WoT    = (ushort*)p; p += (size_t)768*KP*2;            //  1.2 MB
    ushort* qkv    = (ushort*)p; p += (size_t)3*BHROWS*64*2;       // 37.7 MB
    float*  tbuf   = (float*)p;  p += (size_t)3*BHROWS*4;          //  1.2 MB
    float*  ct     = (float*)p;  p += (size_t)NROWS*HEADS*4;       //  0.4 MB
    ushort* merged = (ushort*)p; p += (size_t)NROWS*KP*2;          // 13.1 MB
    ushort* vT     = (ushort*)p; p += (size_t)BH*64*NSEQ*2;        // 12.6 MB
    float*  rowsum = (float*)p;  p += (size_t)12*NROWS*4;          //  0.4 MB

    const size_t SP = (size_t)BHROWS*64;

    conv_x<<<6400, 256, 0, stream>>>(x, xb);
    conv_w<<<dim3(25,24,4), 256, 0, stream>>>(Wq, Wk, Wv, Wo, WcatT, WoT);
    gemm_qkv<<<dim3(64,18), 256, 0, stream>>>(xb, WcatT, qkv, tbuf);
    transpose_v<<<768, 256, 0, stream>>>(qkv + 2*SP, vT);
    lorentz_attn<<<768, 256, 0, stream>>>(qkv, qkv + SP, vT,
                                          tbuf, tbuf + BHROWS, tbuf + 2*BHROWS,
                                          merged, ct);
    time_r_k<<<NROWS/256, 256, 0, stream>>>(ct, merged);
    gemm_out_k<<<dim3(64,6), 256, 0, stream>>>(merged, WoT, out, rowsum);
    out_time<<<NROWS/256, 256, 0, stream>>>(rowsum, out);
}